// Round 1
// baseline (371.775 us; speedup 1.0000x reference)
//
#include <hip/hip_runtime.h>
#include <stdint.h>

#define NNODES 4096
#define FDIM 256
#define NH 4
#define HD 64
#define MWORDS 128  // 4096/32 mask words per row

// ---------------- W transpose (3x 256x256) ----------------
__global__ __launch_bounds__(256) void k_transpose_w(
    const float* __restrict__ Wq, const float* __restrict__ Wk,
    const float* __restrict__ Wv, float* __restrict__ Wt)
{
    __shared__ float tile[32][33];
    int mat = blockIdx.z;
    const float* W = mat == 0 ? Wq : (mat == 1 ? Wk : Wv);
    float* dst = Wt + (size_t)mat * FDIM * FDIM;
    int r0 = blockIdx.y * 32, c0 = blockIdx.x * 32;
    int tx = threadIdx.x, ty = threadIdx.y;  // block (32,8)
    for (int i = ty; i < 32; i += 8)
        tile[i][tx] = W[(size_t)(r0 + i) * FDIM + c0 + tx];
    __syncthreads();
    for (int i = ty; i < 32; i += 8)
        dst[(size_t)(c0 + i) * FDIM + r0 + tx] = tile[tx][i];
}

// ---------------- adjacency bitmask ----------------
__global__ void k_mask_build(const int* __restrict__ ei, int E, uint32_t* __restrict__ mask)
{
    int e = blockIdx.x * 256 + threadIdx.x;
    if (e >= E) return;
    int r = ei[e];
    int c = ei[E + e];
    atomicOr(&mask[(size_t)r * MWORDS + (c >> 5)], 1u << (c & 31));
}

// ---------------- QKV projection (fp32, W^T coalesced) ----------------
#define TN 16
__global__ __launch_bounds__(256) void k_qkv(
    const float* __restrict__ x, const float* __restrict__ Wt,
    const float* __restrict__ bq, const float* __restrict__ bk, const float* __restrict__ bv,
    float* __restrict__ qkv)
{
    int mat = blockIdx.y;
    const float* W = Wt + (size_t)mat * FDIM * FDIM;           // [k][t] layout
    const float* bias = mat == 0 ? bq : (mat == 1 ? bk : bv);
    float* dst = qkv + (size_t)mat * NNODES * FDIM;
    int n0 = blockIdx.x * TN;
    int t = threadIdx.x;
    __shared__ float xl[TN][FDIM + 4];   // +4 keeps 16B row alignment, breaks bank cycles
    for (int f = t; f < TN * (FDIM / 4); f += 256) {
        int n = f >> 6, c4 = f & 63;
        float4 v = ((const float4*)(x + (size_t)(n0 + n) * FDIM))[c4];
        *(float4*)&xl[n][c4 * 4] = v;
    }
    __syncthreads();
    float acc[TN];
    #pragma unroll
    for (int n = 0; n < TN; ++n) acc[n] = 0.f;
    for (int k4 = 0; k4 < FDIM / 4; ++k4) {
        float w0 = W[(size_t)(k4 * 4 + 0) * FDIM + t];
        float w1 = W[(size_t)(k4 * 4 + 1) * FDIM + t];
        float w2 = W[(size_t)(k4 * 4 + 2) * FDIM + t];
        float w3 = W[(size_t)(k4 * 4 + 3) * FDIM + t];
        #pragma unroll
        for (int n = 0; n < TN; ++n) {
            float4 xv = *(const float4*)&xl[n][k4 * 4];
            acc[n] = fmaf(w0, xv.x, acc[n]);
            acc[n] = fmaf(w1, xv.y, acc[n]);
            acc[n] = fmaf(w2, xv.z, acc[n]);
            acc[n] = fmaf(w3, xv.w, acc[n]);
        }
    }
    float bb = bias[t];
    #pragma unroll
    for (int n = 0; n < TN; ++n)
        dst[(size_t)(n0 + n) * FDIM + t] = acc[n] + bb;
}

// ---------------- fused sparse attention + residual + LN + attn-row stream ----------------
__global__ __launch_bounds__(256) void k_attn(
    const float* __restrict__ qkv, const uint32_t* __restrict__ mask,
    const float* __restrict__ x, const float* __restrict__ ln_g, const float* __restrict__ ln_b,
    float* __restrict__ out)
{
    const float* Q = qkv;
    const float* K = qkv + (size_t)NNODES * FDIM;
    const float* V = qkv + 2 * (size_t)NNODES * FDIM;

    __shared__ float q_lds[FDIM];
    __shared__ uint32_t mrow[MWORDS];
    __shared__ unsigned short list[NNODES];
    __shared__ float p_chunk[NH][64];
    __shared__ float red0[256], red1[256];
    __shared__ int cnt_s;

    int n = blockIdx.x;
    int t = threadIdx.x;
    int h = t >> 6, lane = t & 63;   // wave h handles head h

    q_lds[t] = Q[(size_t)n * FDIM + t];
    float xv = x[(size_t)n * FDIM + t];
    if (t < MWORDS) mrow[t] = mask[(size_t)n * MWORDS + t];
    __syncthreads();

    // ---- neighbor compaction (wave 0, deterministic order) ----
    if (t < 64) {
        int total = 0;
        for (int r = 0; r < 2; ++r) {
            int w = r * 64 + t;
            uint32_t bits = mrow[w];
            int c = __popc(bits);
            int scan = c;
            #pragma unroll
            for (int off = 1; off < 64; off <<= 1) {
                int u = __shfl_up(scan, off);
                if (t >= off) scan += u;
            }
            int base = total + scan - c;
            while (bits) {
                int b = __ffs(bits) - 1;
                list[base++] = (unsigned short)(w * 32 + b);
                bits &= bits - 1;
            }
            total += __shfl(scan, 63);
        }
        if (t == 0) cnt_s = total;
    }
    __syncthreads();
    int cnt = cnt_s;   // >= 1 (self-loop)

    const float4* qh = (const float4*)(q_lds + h * HD);

    // ---- pass 1: online softmax stats over neighbors ----
    float mi = -INFINITY, li = 0.f;
    for (int i = lane; i < cnt; i += 64) {
        int m = list[i];
        const float4* kp = (const float4*)(K + (size_t)m * FDIM + h * HD);
        float s = 0.f;
        #pragma unroll
        for (int j = 0; j < HD / 4; ++j) {
            float4 a = qh[j], b = kp[j];
            s += a.x * b.x + a.y * b.y + a.z * b.z + a.w * b.w;
        }
        s *= 0.125f;
        float nm = fmaxf(mi, s);
        li = li * __expf(mi - nm) + __expf(s - nm);
        mi = nm;
    }
    #pragma unroll
    for (int off = 32; off; off >>= 1) {
        float mo = __shfl_xor(mi, off);
        float lo = __shfl_xor(li, off);
        float nm = fmaxf(mi, mo);
        float ea = (nm == -INFINITY) ? 0.f : __expf(mi - nm);  // guard NaN from (-inf)-(-inf)
        float eb = (nm == -INFINITY) ? 0.f : __expf(mo - nm);
        li = li * ea + lo * eb;
        mi = nm;
    }
    float M = mi;
    float Linv = 1.f / li;

    // ---- PV: o[d] = sum_m p_m * V[m, h*64+d] ----
    float o = 0.f;
    for (int base = 0; base < cnt; base += 64) {
        int j = base + lane;
        float p = 0.f;
        if (j < cnt) {
            int m = list[j];
            const float4* kp = (const float4*)(K + (size_t)m * FDIM + h * HD);
            float s = 0.f;
            #pragma unroll
            for (int jj = 0; jj < HD / 4; ++jj) {
                float4 a = qh[jj], b = kp[jj];
                s += a.x * b.x + a.y * b.y + a.z * b.z + a.w * b.w;
            }
            p = __expf(s * 0.125f - M) * Linv;
        }
        p_chunk[h][lane] = p;
        __syncthreads();   // cnt uniform across block -> safe
        int lim = min(64, cnt - base);
        for (int jj = 0; jj < lim; ++jj) {
            int m = list[base + jj];
            o = fmaf(p_chunk[h][jj], V[(size_t)m * FDIM + h * HD + lane], o);
        }
        __syncthreads();
    }

    // ---- residual + LayerNorm ----
    float y = o + xv;
    red0[t] = y;
    red1[t] = y * y;
    __syncthreads();
    for (int s2 = 128; s2 > 0; s2 >>= 1) {
        if (t < s2) { red0[t] += red0[t + s2]; red1[t] += red1[t + s2]; }
        __syncthreads();
    }
    float mu = red0[0] * (1.f / 256.f);
    float var = red1[0] * (1.f / 256.f) - mu * mu;
    float outv = (y - mu) * rsqrtf(var + 1e-5f) * ln_g[t] + ln_b[t];
    out[(size_t)n * FDIM + t] = outv;

    // ---- stream full attn row for this head (zeros inline, coalesced float4) ----
    float* attn = out + (size_t)NNODES * FDIM;
    float* rowp = attn + ((size_t)h * NNODES + n) * NNODES;
    for (int it = 0; it < NNODES / 256; ++it) {   // 16 iterations
        int c = (it * 64 + lane) * 4;
        uint32_t nib = (mrow[c >> 5] >> (c & 31)) & 0xFu;
        float4 v = make_float4(0.f, 0.f, 0.f, 0.f);
        if (nib) {
            float pv[4] = {0.f, 0.f, 0.f, 0.f};
            #pragma unroll
            for (int j = 0; j < 4; ++j) {
                if ((nib >> j) & 1u) {
                    int m = c + j;
                    const float4* kp = (const float4*)(K + (size_t)m * FDIM + h * HD);
                    float s = 0.f;
                    #pragma unroll
                    for (int jj = 0; jj < HD / 4; ++jj) {
                        float4 a = qh[jj], b = kp[jj];
                        s += a.x * b.x + a.y * b.y + a.z * b.z + a.w * b.w;
                    }
                    pv[j] = __expf(s * 0.125f - M) * Linv;
                }
            }
            v = make_float4(pv[0], pv[1], pv[2], pv[3]);
        }
        *(float4*)&rowp[c] = v;
    }
}

extern "C" void kernel_launch(void* const* d_in, const int* in_sizes, int n_in,
                              void* d_out, int out_size, void* d_ws, size_t ws_size,
                              hipStream_t stream)
{
    const float* x    = (const float*)d_in[0];
    const int*   ei   = (const int*)d_in[1];
    const float* Wq   = (const float*)d_in[2];
    const float* bq   = (const float*)d_in[3];
    const float* Wk   = (const float*)d_in[4];
    const float* bk   = (const float*)d_in[5];
    const float* Wv   = (const float*)d_in[6];
    const float* bv   = (const float*)d_in[7];
    const float* ln_g = (const float*)d_in[8];
    const float* ln_b = (const float*)d_in[9];
    float* out = (float*)d_out;

    int E = in_sizes[1] / 2;   // 135168 = 131072 random + 4096 self-loops

    // workspace layout (floats): Wt[3*256*256] | QKV[3*4096*256] | mask[4096*128 u32]
    float* Wt  = (float*)d_ws;
    float* qkv = Wt + 3 * FDIM * FDIM;
    uint32_t* mask = (uint32_t*)(qkv + 3 * (size_t)NNODES * FDIM);

    hipMemsetAsync(mask, 0, (size_t)NNODES * MWORDS * sizeof(uint32_t), stream);

    dim3 tb(32, 8);
    k_transpose_w<<<dim3(8, 8, 3), tb, 0, stream>>>(Wq, Wk, Wv, Wt);
    k_mask_build<<<(E + 255) / 256, 256, 0, stream>>>(ei, E, mask);
    k_qkv<<<dim3(NNODES / TN, 3), 256, 0, stream>>>(x, Wt, bq, bk, bv, qkv);
    k_attn<<<NNODES, 256, 0, stream>>>(qkv, mask, x, ln_g, ln_b, out);
}

// Round 2
// 312.701 us; speedup vs baseline: 1.1889x; 1.1889x over previous
//
#include <hip/hip_runtime.h>
#include <stdint.h>

#define NNODES 4096
#define FDIM 256
#define NH 4
#define HD 64
#define MWORDS 128  // 4096/32 mask words per row
#define SCAP 512    // score cache per head (fallback recompute beyond)

typedef float f4 __attribute__((ext_vector_type(4)));

// ---------------- W transpose (3x 256x256) ----------------
__global__ __launch_bounds__(256) void k_transpose_w(
    const float* __restrict__ Wq, const float* __restrict__ Wk,
    const float* __restrict__ Wv, float* __restrict__ Wt)
{
    __shared__ float tile[32][33];
    int mat = blockIdx.z;
    const float* W = mat == 0 ? Wq : (mat == 1 ? Wk : Wv);
    float* dst = Wt + (size_t)mat * FDIM * FDIM;
    int r0 = blockIdx.y * 32, c0 = blockIdx.x * 32;
    int tx = threadIdx.x, ty = threadIdx.y;  // block (32,8)
    for (int i = ty; i < 32; i += 8)
        tile[i][tx] = W[(size_t)(r0 + i) * FDIM + c0 + tx];
    __syncthreads();
    for (int i = ty; i < 32; i += 8)
        dst[(size_t)(c0 + i) * FDIM + r0 + tx] = tile[tx][i];
}

// ---------------- adjacency bitmask ----------------
__global__ void k_mask_build(const int* __restrict__ ei, int E, uint32_t* __restrict__ mask)
{
    int e = blockIdx.x * 256 + threadIdx.x;
    if (e >= E) return;
    int r = ei[e];
    int c = ei[E + e];
    atomicOr(&mask[(size_t)r * MWORDS + (c >> 5)], 1u << (c & 31));
}

// ---------------- QKV projection (fp32, W^T coalesced) ----------------
#define TN 16
__global__ __launch_bounds__(256) void k_qkv(
    const float* __restrict__ x, const float* __restrict__ Wt,
    const float* __restrict__ bq, const float* __restrict__ bk, const float* __restrict__ bv,
    float* __restrict__ qkv)
{
    int mat = blockIdx.y;
    const float* W = Wt + (size_t)mat * FDIM * FDIM;           // [k][t] layout
    const float* bias = mat == 0 ? bq : (mat == 1 ? bk : bv);
    float* dst = qkv + (size_t)mat * NNODES * FDIM;
    int n0 = blockIdx.x * TN;
    int t = threadIdx.x;
    __shared__ float xl[TN][FDIM + 4];
    for (int f = t; f < TN * (FDIM / 4); f += 256) {
        int n = f >> 6, c4 = f & 63;
        float4 v = ((const float4*)(x + (size_t)(n0 + n) * FDIM))[c4];
        *(float4*)&xl[n][c4 * 4] = v;
    }
    __syncthreads();
    float acc[TN];
    #pragma unroll
    for (int n = 0; n < TN; ++n) acc[n] = 0.f;
    for (int k4 = 0; k4 < FDIM / 4; ++k4) {
        float w0 = W[(size_t)(k4 * 4 + 0) * FDIM + t];
        float w1 = W[(size_t)(k4 * 4 + 1) * FDIM + t];
        float w2 = W[(size_t)(k4 * 4 + 2) * FDIM + t];
        float w3 = W[(size_t)(k4 * 4 + 3) * FDIM + t];
        #pragma unroll
        for (int n = 0; n < TN; ++n) {
            float4 xv = *(const float4*)&xl[n][k4 * 4];
            acc[n] = fmaf(w0, xv.x, acc[n]);
            acc[n] = fmaf(w1, xv.y, acc[n]);
            acc[n] = fmaf(w2, xv.z, acc[n]);
            acc[n] = fmaf(w3, xv.w, acc[n]);
        }
    }
    float bb = bias[t];
    #pragma unroll
    for (int n = 0; n < TN; ++n)
        dst[(size_t)(n0 + n) * FDIM + t] = acc[n] + bb;
}

// ---------------- sparse attention + residual + LN (no dense stream) ----------------
__global__ __launch_bounds__(256) void k_attn(
    const float* __restrict__ qkv, const uint32_t* __restrict__ mask,
    const float* __restrict__ x, const float* __restrict__ ln_g, const float* __restrict__ ln_b,
    float* __restrict__ out, float* __restrict__ stats)
{
    const float* Q = qkv;
    const float* K = qkv + (size_t)NNODES * FDIM;
    const float* V = qkv + 2 * (size_t)NNODES * FDIM;

    __shared__ float q_lds[FDIM];
    __shared__ uint32_t mrow[MWORDS];
    __shared__ unsigned short list[NNODES];
    __shared__ float sv[NH][SCAP];
    __shared__ float red0[NH], red1[NH];
    __shared__ int cnt_s;

    int n = blockIdx.x;
    int t = threadIdx.x;
    int h = t >> 6, lane = t & 63;   // wave h handles head h

    q_lds[t] = Q[(size_t)n * FDIM + t];
    float xv = x[(size_t)n * FDIM + t];
    if (t < MWORDS) mrow[t] = mask[(size_t)n * MWORDS + t];
    __syncthreads();

    // ---- neighbor compaction (wave 0, deterministic order) ----
    if (t < 64) {
        int total = 0;
        for (int r = 0; r < 2; ++r) {
            int w = r * 64 + t;
            uint32_t bits = mrow[w];
            int c = __popc(bits);
            int scan = c;
            #pragma unroll
            for (int off = 1; off < 64; off <<= 1) {
                int u = __shfl_up(scan, off);
                if (t >= off) scan += u;
            }
            int base = total + scan - c;
            while (bits) {
                int b = __ffs(bits) - 1;
                list[base++] = (unsigned short)(w * 32 + b);
                bits &= bits - 1;
            }
            total += __shfl(scan, 63);
        }
        if (t == 0) cnt_s = total;
    }
    __syncthreads();
    int cnt = cnt_s;   // >= 1 (self-loop)

    const float4* qh = (const float4*)(q_lds + h * HD);

    // ---- pass 1: scores + online softmax stats ----
    float mi = -INFINITY, li = 0.f;
    for (int i = lane; i < cnt; i += 64) {
        int m = list[i];
        const float4* kp = (const float4*)(K + (size_t)m * FDIM + h * HD);
        float s = 0.f;
        #pragma unroll
        for (int j = 0; j < HD / 4; ++j) {
            float4 a = qh[j], b = kp[j];
            s += a.x * b.x + a.y * b.y + a.z * b.z + a.w * b.w;
        }
        s *= 0.125f;
        if (i < SCAP) sv[h][i] = s;
        float nm = fmaxf(mi, s);
        li = li * __expf(mi - nm) + __expf(s - nm);
        mi = nm;
    }
    #pragma unroll
    for (int off = 32; off; off >>= 1) {
        float mo = __shfl_xor(mi, off);
        float lo = __shfl_xor(li, off);
        float nm = fmaxf(mi, mo);
        float ea = (nm == -INFINITY) ? 0.f : __expf(mi - nm);
        float eb = (nm == -INFINITY) ? 0.f : __expf(mo - nm);
        li = li * ea + lo * eb;
        mi = nm;
    }
    float M = mi;
    float Linv = 1.f / li;
    if (lane == 0) {
        stats[((size_t)h * NNODES + n) * 2 + 0] = M;
        stats[((size_t)h * NNODES + n) * 2 + 1] = Linv;
    }

    // ---- convert cached scores to probabilities (same wave: no barrier) ----
    int cm = min(cnt, SCAP);
    for (int i = lane; i < cm; i += 64)
        sv[h][i] = __expf(sv[h][i] - M) * Linv;

    // ---- PV: lane = output dim; 4 independent accumulators ----
    const float* vb = V + (size_t)h * HD + lane;
    float o0 = 0.f, o1 = 0.f, o2 = 0.f, o3 = 0.f;
    int j = 0;
    for (; j + 3 < cm; j += 4) {
        int m0 = list[j], m1 = list[j + 1], m2 = list[j + 2], m3 = list[j + 3];
        float p0 = sv[h][j], p1 = sv[h][j + 1], p2 = sv[h][j + 2], p3 = sv[h][j + 3];
        o0 = fmaf(p0, vb[(size_t)m0 * FDIM], o0);
        o1 = fmaf(p1, vb[(size_t)m1 * FDIM], o1);
        o2 = fmaf(p2, vb[(size_t)m2 * FDIM], o2);
        o3 = fmaf(p3, vb[(size_t)m3 * FDIM], o3);
    }
    for (; j < cm; ++j)
        o0 = fmaf(sv[h][j], vb[(size_t)list[j] * FDIM], o0);
    for (; j < cnt; ++j) {  // overflow fallback (degree > SCAP): recompute score
        int m = list[j];
        const float4* kp = (const float4*)(K + (size_t)m * FDIM + h * HD);
        float s = 0.f;
        #pragma unroll
        for (int jj = 0; jj < HD / 4; ++jj) {
            float4 a = qh[jj], b = kp[jj];
            s += a.x * b.x + a.y * b.y + a.z * b.z + a.w * b.w;
        }
        o0 = fmaf(__expf(s * 0.125f - M) * Linv, vb[(size_t)m * FDIM], o0);
    }
    float o = (o0 + o1) + (o2 + o3);

    // ---- residual + LayerNorm (wave shuffle reduce, 1 barrier) ----
    float y = o + xv;
    float s1 = y, s2 = y * y;
    #pragma unroll
    for (int off = 32; off; off >>= 1) {
        s1 += __shfl_xor(s1, off);
        s2 += __shfl_xor(s2, off);
    }
    if (lane == 0) { red0[h] = s1; red1[h] = s2; }
    __syncthreads();
    float ts1 = (red0[0] + red0[1]) + (red0[2] + red0[3]);
    float ts2 = (red1[0] + red1[1]) + (red1[2] + red1[3]);
    float mu = ts1 * (1.f / 256.f);
    float var = ts2 * (1.f / 256.f) - mu * mu;
    out[(size_t)n * FDIM + t] = (y - mu) * rsqrtf(var + 1e-5f) * ln_g[t] + ln_b[t];
}

// ---------------- dense attn-row fill: one block per (head,row) ----------------
__global__ __launch_bounds__(256) void k_fill(
    const float* __restrict__ qkv, const uint32_t* __restrict__ mask,
    const float* __restrict__ stats, float* __restrict__ attn)
{
    const float* Q = qkv;
    const float* K = qkv + (size_t)NNODES * FDIM;

    __shared__ float qh[HD];
    __shared__ uint32_t mrow[MWORDS];
    __shared__ float Ms, Ls;

    int r = blockIdx.x;            // r = h*4096 + n
    int h = r >> 12, n = r & 4095;
    int t = threadIdx.x;

    if (t < HD) qh[t] = Q[(size_t)n * FDIM + h * HD + t];
    else if (t < HD + MWORDS) mrow[t - HD] = mask[(size_t)n * MWORDS + (t - HD)];
    else if (t == HD + MWORDS) { Ms = stats[(size_t)r * 2]; Ls = stats[(size_t)r * 2 + 1]; }
    __syncthreads();

    float M = Ms, Linv = Ls;
    float* rowp = attn + (size_t)r * NNODES;

    #pragma unroll
    for (int it = 0; it < NNODES / (256 * 4); ++it) {   // 4 iterations
        int c = (it * 256 + t) * 4;
        uint32_t nib = (mrow[c >> 5] >> (c & 31)) & 0xFu;
        f4 v = {0.f, 0.f, 0.f, 0.f};
        if (nib) {
            #pragma unroll
            for (int j = 0; j < 4; ++j) {
                if ((nib >> j) & 1u) {
                    const float4* kp = (const float4*)(K + (size_t)(c + j) * FDIM + h * HD);
                    float s = 0.f;
                    #pragma unroll
                    for (int q4 = 0; q4 < HD / 4; ++q4) {
                        float4 a = *(const float4*)&qh[q4 * 4];
                        float4 b = kp[q4];
                        s += a.x * b.x + a.y * b.y + a.z * b.z + a.w * b.w;
                    }
                    v[j] = __expf(s * 0.125f - M) * Linv;
                }
            }
        }
        __builtin_nontemporal_store(v, (f4*)(rowp + c));
    }
}

extern "C" void kernel_launch(void* const* d_in, const int* in_sizes, int n_in,
                              void* d_out, int out_size, void* d_ws, size_t ws_size,
                              hipStream_t stream)
{
    const float* x    = (const float*)d_in[0];
    const int*   ei   = (const int*)d_in[1];
    const float* Wq   = (const float*)d_in[2];
    const float* bq   = (const float*)d_in[3];
    const float* Wk   = (const float*)d_in[4];
    const float* bk   = (const float*)d_in[5];
    const float* Wv   = (const float*)d_in[6];
    const float* bv   = (const float*)d_in[7];
    const float* ln_g = (const float*)d_in[8];
    const float* ln_b = (const float*)d_in[9];
    float* out = (float*)d_out;
    float* attn = out + (size_t)NNODES * FDIM;

    int E = in_sizes[1] / 2;

    // ws layout (floats): Wt[3*256*256] | QKV[3*4096*256] | mask[4096*128 u32] | stats[4*4096*2]
    float* Wt  = (float*)d_ws;
    float* qkv = Wt + 3 * FDIM * FDIM;
    uint32_t* mask = (uint32_t*)(qkv + 3 * (size_t)NNODES * FDIM);
    float* stats = (float*)(mask + (size_t)NNODES * MWORDS);

    hipMemsetAsync(mask, 0, (size_t)NNODES * MWORDS * sizeof(uint32_t), stream);

    dim3 tb(32, 8);
    k_transpose_w<<<dim3(8, 8, 3), tb, 0, stream>>>(Wq, Wk, Wv, Wt);
    k_mask_build<<<(E + 255) / 256, 256, 0, stream>>>(ei, E, mask);
    k_qkv<<<dim3(NNODES / TN, 3), 256, 0, stream>>>(x, Wt, bq, bk, bv, qkv);
    k_attn<<<NNODES, 256, 0, stream>>>(qkv, mask, x, ln_g, ln_b, out, stats);
    k_fill<<<NH * NNODES, 256, 0, stream>>>(qkv, mask, stats, attn);
}

// Round 3
// 221.276 us; speedup vs baseline: 1.6801x; 1.4132x over previous
//
#include <hip/hip_runtime.h>
#include <stdint.h>

#define NNODES 4096
#define FDIM 256
#define NH 4
#define HD 64
#define MWORDS 128  // 4096/32 mask words per row
#define SCAP 512    // score cache per head (fallback recompute beyond)

typedef float f4 __attribute__((ext_vector_type(4)));

// ---------------- W transpose (3x 256x256) ----------------
__global__ __launch_bounds__(256) void k_transpose_w(
    const float* __restrict__ Wq, const float* __restrict__ Wk,
    const float* __restrict__ Wv, float* __restrict__ Wt)
{
    __shared__ float tile[32][33];
    int mat = blockIdx.z;
    const float* W = mat == 0 ? Wq : (mat == 1 ? Wk : Wv);
    float* dst = Wt + (size_t)mat * FDIM * FDIM;
    int r0 = blockIdx.y * 32, c0 = blockIdx.x * 32;
    int tx = threadIdx.x, ty = threadIdx.y;  // block (32,8)
    for (int i = ty; i < 32; i += 8)
        tile[i][tx] = W[(size_t)(r0 + i) * FDIM + c0 + tx];
    __syncthreads();
    for (int i = ty; i < 32; i += 8)
        dst[(size_t)(c0 + i) * FDIM + r0 + tx] = tile[tx][i];
}

// ---------------- adjacency bitmask ----------------
__global__ void k_mask_build(const int* __restrict__ ei, int E, uint32_t* __restrict__ mask)
{
    int e = blockIdx.x * 256 + threadIdx.x;
    if (e >= E) return;
    int r = ei[e];
    int c = ei[E + e];
    atomicOr(&mask[(size_t)r * MWORDS + (c >> 5)], 1u << (c & 31));
}

// ---------------- QKV projection (fp32, W^T coalesced) ----------------
#define TN 16
__global__ __launch_bounds__(256) void k_qkv(
    const float* __restrict__ x, const float* __restrict__ Wt,
    const float* __restrict__ bq, const float* __restrict__ bk, const float* __restrict__ bv,
    float* __restrict__ qkv)
{
    int mat = blockIdx.y;
    const float* W = Wt + (size_t)mat * FDIM * FDIM;           // [k][t] layout
    const float* bias = mat == 0 ? bq : (mat == 1 ? bk : bv);
    float* dst = qkv + (size_t)mat * NNODES * FDIM;
    int n0 = blockIdx.x * TN;
    int t = threadIdx.x;
    __shared__ float xl[TN][FDIM + 4];
    for (int f = t; f < TN * (FDIM / 4); f += 256) {
        int n = f >> 6, c4 = f & 63;
        float4 v = ((const float4*)(x + (size_t)(n0 + n) * FDIM))[c4];
        *(float4*)&xl[n][c4 * 4] = v;
    }
    __syncthreads();
    float acc[TN];
    #pragma unroll
    for (int n = 0; n < TN; ++n) acc[n] = 0.f;
    for (int k4 = 0; k4 < FDIM / 4; ++k4) {
        float w0 = W[(size_t)(k4 * 4 + 0) * FDIM + t];
        float w1 = W[(size_t)(k4 * 4 + 1) * FDIM + t];
        float w2 = W[(size_t)(k4 * 4 + 2) * FDIM + t];
        float w3 = W[(size_t)(k4 * 4 + 3) * FDIM + t];
        #pragma unroll
        for (int n = 0; n < TN; ++n) {
            float4 xv = *(const float4*)&xl[n][k4 * 4];
            acc[n] = fmaf(w0, xv.x, acc[n]);
            acc[n] = fmaf(w1, xv.y, acc[n]);
            acc[n] = fmaf(w2, xv.z, acc[n]);
            acc[n] = fmaf(w3, xv.w, acc[n]);
        }
    }
    float bb = bias[t];
    #pragma unroll
    for (int n = 0; n < TN; ++n)
        dst[(size_t)(n0 + n) * FDIM + t] = acc[n] + bb;
}

// ---------------- sparse attention + residual + LN ----------------
__global__ __launch_bounds__(256) void k_attn(
    const float* __restrict__ qkv, const uint32_t* __restrict__ mask,
    const float* __restrict__ x, const float* __restrict__ ln_g, const float* __restrict__ ln_b,
    float* __restrict__ out, float* __restrict__ stats)
{
    const float* Q = qkv;
    const float* K = qkv + (size_t)NNODES * FDIM;
    const float* V = qkv + 2 * (size_t)NNODES * FDIM;

    __shared__ float q_lds[FDIM];
    __shared__ uint32_t mrow[MWORDS];
    __shared__ unsigned short list[NNODES];
    __shared__ float sv[NH][SCAP];
    __shared__ float red0[NH], red1[NH];
    __shared__ int cnt_s;

    int n = blockIdx.x;
    int t = threadIdx.x;
    int h = t >> 6, lane = t & 63;   // wave h handles head h

    q_lds[t] = Q[(size_t)n * FDIM + t];
    float xv = x[(size_t)n * FDIM + t];
    if (t < MWORDS) mrow[t] = mask[(size_t)n * MWORDS + t];
    __syncthreads();

    // ---- neighbor compaction (wave 0, deterministic order) ----
    if (t < 64) {
        int total = 0;
        for (int r = 0; r < 2; ++r) {
            int w = r * 64 + t;
            uint32_t bits = mrow[w];
            int c = __popc(bits);
            int scan = c;
            #pragma unroll
            for (int off = 1; off < 64; off <<= 1) {
                int u = __shfl_up(scan, off);
                if (t >= off) scan += u;
            }
            int base = total + scan - c;
            while (bits) {
                int b = __ffs(bits) - 1;
                list[base++] = (unsigned short)(w * 32 + b);
                bits &= bits - 1;
            }
            total += __shfl(scan, 63);
        }
        if (t == 0) cnt_s = total;
    }
    __syncthreads();
    int cnt = cnt_s;   // >= 1 (self-loop)

    const float4* qh = (const float4*)(q_lds + h * HD);

    // ---- pass 1: scores + online softmax stats ----
    float mi = -INFINITY, li = 0.f;
    for (int i = lane; i < cnt; i += 64) {
        int m = list[i];
        const float4* kp = (const float4*)(K + (size_t)m * FDIM + h * HD);
        float s = 0.f;
        #pragma unroll
        for (int j = 0; j < HD / 4; ++j) {
            float4 a = qh[j], b = kp[j];
            s += a.x * b.x + a.y * b.y + a.z * b.z + a.w * b.w;
        }
        s *= 0.125f;
        if (i < SCAP) sv[h][i] = s;
        float nm = fmaxf(mi, s);
        li = li * __expf(mi - nm) + __expf(s - nm);
        mi = nm;
    }
    #pragma unroll
    for (int off = 32; off; off >>= 1) {
        float mo = __shfl_xor(mi, off);
        float lo = __shfl_xor(li, off);
        float nm = fmaxf(mi, mo);
        float ea = (nm == -INFINITY) ? 0.f : __expf(mi - nm);
        float eb = (nm == -INFINITY) ? 0.f : __expf(mo - nm);
        li = li * ea + lo * eb;
        mi = nm;
    }
    float M = mi;
    float Linv = 1.f / li;
    if (lane == 0) {
        stats[((size_t)h * NNODES + n) * 2 + 0] = M;
        stats[((size_t)h * NNODES + n) * 2 + 1] = Linv;
    }

    // ---- convert cached scores to probabilities (same wave: no barrier) ----
    int cm = min(cnt, SCAP);
    for (int i = lane; i < cm; i += 64)
        sv[h][i] = __expf(sv[h][i] - M) * Linv;

    // ---- PV: lane = output dim; 4 independent accumulators ----
    const float* vb = V + (size_t)h * HD + lane;
    float o0 = 0.f, o1 = 0.f, o2 = 0.f, o3 = 0.f;
    int j = 0;
    for (; j + 3 < cm; j += 4) {
        int m0 = list[j], m1 = list[j + 1], m2 = list[j + 2], m3 = list[j + 3];
        float p0 = sv[h][j], p1 = sv[h][j + 1], p2 = sv[h][j + 2], p3 = sv[h][j + 3];
        o0 = fmaf(p0, vb[(size_t)m0 * FDIM], o0);
        o1 = fmaf(p1, vb[(size_t)m1 * FDIM], o1);
        o2 = fmaf(p2, vb[(size_t)m2 * FDIM], o2);
        o3 = fmaf(p3, vb[(size_t)m3 * FDIM], o3);
    }
    for (; j < cm; ++j)
        o0 = fmaf(sv[h][j], vb[(size_t)list[j] * FDIM], o0);
    for (; j < cnt; ++j) {  // overflow fallback (degree > SCAP): recompute score
        int m = list[j];
        const float4* kp = (const float4*)(K + (size_t)m * FDIM + h * HD);
        float s = 0.f;
        #pragma unroll
        for (int jj = 0; jj < HD / 4; ++jj) {
            float4 a = qh[jj], b = kp[jj];
            s += a.x * b.x + a.y * b.y + a.z * b.z + a.w * b.w;
        }
        o0 = fmaf(__expf(s * 0.125f - M) * Linv, vb[(size_t)m * FDIM], o0);
    }
    float o = (o0 + o1) + (o2 + o3);

    // ---- residual + LayerNorm (wave shuffle reduce, 1 barrier) ----
    float y = o + xv;
    float s1 = y, s2 = y * y;
    #pragma unroll
    for (int off = 32; off; off >>= 1) {
        s1 += __shfl_xor(s1, off);
        s2 += __shfl_xor(s2, off);
    }
    if (lane == 0) { red0[h] = s1; red1[h] = s2; }
    __syncthreads();
    float ts1 = (red0[0] + red0[1]) + (red0[2] + red0[3]);
    float ts2 = (red1[0] + red1[1]) + (red1[2] + red1[3]);
    float mu = ts1 * (1.f / 256.f);
    float var = ts2 * (1.f / 256.f) - mu * mu;
    out[(size_t)n * FDIM + t] = (y - mu) * rsqrtf(var + 1e-5f) * ln_g[t] + ln_b[t];
}

// ---------------- nonzero scatter: one thread per (edge, head) ----------------
__global__ __launch_bounds__(256) void k_scatter(
    const int* __restrict__ ei, int E,
    const float* __restrict__ qkv, const float* __restrict__ stats,
    float* __restrict__ attn)
{
    int idx = blockIdx.x * 256 + threadIdx.x;
    if (idx >= E * NH) return;
    int e = idx >> 2;
    int h = idx & 3;          // 4 consecutive threads share one edge -> coalesced row reads
    int r = ei[e];
    int c = ei[E + e];

    const float* Q = qkv;
    const float* K = qkv + (size_t)NNODES * FDIM;
    const float4* qp = (const float4*)(Q + (size_t)r * FDIM + h * HD);
    const float4* kp = (const float4*)(K + (size_t)c * FDIM + h * HD);
    float s = 0.f;
    #pragma unroll
    for (int j = 0; j < HD / 4; ++j) {
        float4 a = qp[j], b = kp[j];
        s += a.x * b.x + a.y * b.y + a.z * b.z + a.w * b.w;
    }
    size_t row = (size_t)h * NNODES + r;
    float M = stats[row * 2 + 0];
    float Linv = stats[row * 2 + 1];
    // duplicates in the edge list write the same value -> benign race
    attn[row * NNODES + c] = __expf(s * 0.125f - M) * Linv;
}

extern "C" void kernel_launch(void* const* d_in, const int* in_sizes, int n_in,
                              void* d_out, int out_size, void* d_ws, size_t ws_size,
                              hipStream_t stream)
{
    const float* x    = (const float*)d_in[0];
    const int*   ei   = (const int*)d_in[1];
    const float* Wq   = (const float*)d_in[2];
    const float* bq   = (const float*)d_in[3];
    const float* Wk   = (const float*)d_in[4];
    const float* bk   = (const float*)d_in[5];
    const float* Wv   = (const float*)d_in[6];
    const float* bv   = (const float*)d_in[7];
    const float* ln_g = (const float*)d_in[8];
    const float* ln_b = (const float*)d_in[9];
    float* out = (float*)d_out;
    float* attn = out + (size_t)NNODES * FDIM;

    int E = in_sizes[1] / 2;

    // ws layout (floats): Wt[3*256*256] | QKV[3*4096*256] | mask[4096*128 u32] | stats[4*4096*2]
    float* Wt  = (float*)d_ws;
    float* qkv = Wt + 3 * FDIM * FDIM;
    uint32_t* mask = (uint32_t*)(qkv + 3 * (size_t)NNODES * FDIM);
    float* stats = (float*)(mask + (size_t)NNODES * MWORDS);

    // bulk-zero the dense attn tensor with AMD's tuned fill (ground-truth fill BW)
    hipMemsetAsync(attn, 0, (size_t)NH * NNODES * NNODES * sizeof(float), stream);
    hipMemsetAsync(mask, 0, (size_t)NNODES * MWORDS * sizeof(uint32_t), stream);

    dim3 tb(32, 8);
    k_transpose_w<<<dim3(8, 8, 3), tb, 0, stream>>>(Wq, Wk, Wv, Wt);
    k_mask_build<<<(E + 255) / 256, 256, 0, stream>>>(ei, E, mask);
    k_qkv<<<dim3(NNODES / TN, 3), 256, 0, stream>>>(x, Wt, bq, bk, bv, qkv);
    k_attn<<<NNODES, 256, 0, stream>>>(qkv, mask, x, ln_g, ln_b, out, stats);
    k_scatter<<<(E * NH + 255) / 256, 256, 0, stream>>>(ei, E, qkv, stats, attn);
}

// Round 4
// 211.933 us; speedup vs baseline: 1.7542x; 1.0441x over previous
//
#include <hip/hip_runtime.h>
#include <stdint.h>

#define NNODES 4096
#define FDIM 256
#define NH 4
#define HD 64
#define MWORDS 128   // 4096/32 mask words per row
#define SCAP 512     // score cache per head (fallback recompute beyond)
#define TOTROWS (NH * NNODES)          // 16384 attn rows (16 KB each)
#define ROW4 (NNODES / 4)              // 1024 float4 per row
#define R0 5120                        // fill split 1 (rows)
#define R1 13824                       // fill split 2 (rows)
#define NFB 2048                       // filler blocks per dispatch

typedef float f4 __attribute__((ext_vector_type(4)));

// grid-stride zero fill over float4 range [beg, end)
__device__ __forceinline__ void fill_zero(f4* __restrict__ attn4, size_t beg, size_t end,
                                          int fid, int t)
{
    f4 z = {0.f, 0.f, 0.f, 0.f};
    size_t stride = (size_t)NFB * 256;
    for (size_t i = beg + (size_t)fid * 256 + t; i < end; i += stride)
        attn4[i] = z;
}

// ---------------- W transpose (3x 256x256) ----------------
__global__ __launch_bounds__(256) void k_transpose_w(
    const float* __restrict__ Wq, const float* __restrict__ Wk,
    const float* __restrict__ Wv, float* __restrict__ Wt)
{
    __shared__ float tile[32][33];
    int mat = blockIdx.z;
    const float* W = mat == 0 ? Wq : (mat == 1 ? Wk : Wv);
    float* dst = Wt + (size_t)mat * FDIM * FDIM;
    int r0 = blockIdx.y * 32, c0 = blockIdx.x * 32;
    int tx = threadIdx.x, ty = threadIdx.y;  // block (32,8)
    for (int i = ty; i < 32; i += 8)
        tile[i][tx] = W[(size_t)(r0 + i) * FDIM + c0 + tx];
    __syncthreads();
    for (int i = ty; i < 32; i += 8)
        dst[(size_t)(c0 + i) * FDIM + r0 + tx] = tile[tx][i];
}

// ---------------- adjacency bitmask ----------------
__global__ void k_mask_build(const int* __restrict__ ei, int E, uint32_t* __restrict__ mask)
{
    int e = blockIdx.x * 256 + threadIdx.x;
    if (e >= E) return;
    int r = ei[e];
    int c = ei[E + e];
    atomicOr(&mask[(size_t)r * MWORDS + (c >> 5)], 1u << (c & 31));
}

// ---------------- QKV projection + fill rows [0, R0) ----------------
#define TN 16
__global__ __launch_bounds__(256) void k_qkv_fill(
    const float* __restrict__ x, const float* __restrict__ Wt,
    const float* __restrict__ bq, const float* __restrict__ bk, const float* __restrict__ bv,
    float* __restrict__ qkv, float* __restrict__ attn)
{
    int t = threadIdx.x;
    if (blockIdx.x >= 3 * (NNODES / TN)) {   // filler blocks
        fill_zero((f4*)attn, 0, (size_t)R0 * ROW4, blockIdx.x - 3 * (NNODES / TN), t);
        return;
    }
    int mat = blockIdx.x >> 8;               // NNODES/TN == 256 blocks per matrix
    int n0 = (blockIdx.x & 255) * TN;
    const float* W = Wt + (size_t)mat * FDIM * FDIM;   // [k][t]
    const float* bias = mat == 0 ? bq : (mat == 1 ? bk : bv);
    float* dst = qkv + (size_t)mat * NNODES * FDIM;
    __shared__ float xl[TN][FDIM + 4];
    for (int f = t; f < TN * (FDIM / 4); f += 256) {
        int n = f >> 6, c4 = f & 63;
        float4 v = ((const float4*)(x + (size_t)(n0 + n) * FDIM))[c4];
        *(float4*)&xl[n][c4 * 4] = v;
    }
    __syncthreads();
    float acc[TN];
    #pragma unroll
    for (int n = 0; n < TN; ++n) acc[n] = 0.f;
    for (int k4 = 0; k4 < FDIM / 4; ++k4) {
        float w0 = W[(size_t)(k4 * 4 + 0) * FDIM + t];
        float w1 = W[(size_t)(k4 * 4 + 1) * FDIM + t];
        float w2 = W[(size_t)(k4 * 4 + 2) * FDIM + t];
        float w3 = W[(size_t)(k4 * 4 + 3) * FDIM + t];
        #pragma unroll
        for (int n = 0; n < TN; ++n) {
            float4 xv = *(const float4*)&xl[n][k4 * 4];
            acc[n] = fmaf(w0, xv.x, acc[n]);
            acc[n] = fmaf(w1, xv.y, acc[n]);
            acc[n] = fmaf(w2, xv.z, acc[n]);
            acc[n] = fmaf(w3, xv.w, acc[n]);
        }
    }
    float bb = bias[t];
    #pragma unroll
    for (int n = 0; n < TN; ++n)
        dst[(size_t)(n0 + n) * FDIM + t] = acc[n] + bb;
}

// ---------------- sparse attention + residual + LN, + fill rows [R0, R1) ----------------
__global__ __launch_bounds__(256) void k_attn_fill(
    const float* __restrict__ qkv, const uint32_t* __restrict__ mask,
    const float* __restrict__ x, const float* __restrict__ ln_g, const float* __restrict__ ln_b,
    float* __restrict__ out, float* __restrict__ stats, float* __restrict__ attn)
{
    int t = threadIdx.x;
    if (blockIdx.x >= NNODES) {              // filler blocks
        fill_zero((f4*)attn, (size_t)R0 * ROW4, (size_t)R1 * ROW4, blockIdx.x - NNODES, t);
        return;
    }

    const float* Q = qkv;
    const float* K = qkv + (size_t)NNODES * FDIM;
    const float* V = qkv + 2 * (size_t)NNODES * FDIM;

    __shared__ float q_lds[FDIM];
    __shared__ uint32_t mrow[MWORDS];
    __shared__ unsigned short list[NNODES];
    __shared__ float sv[NH][SCAP];
    __shared__ float red0[NH], red1[NH];
    __shared__ int cnt_s;

    int n = blockIdx.x;
    int h = t >> 6, lane = t & 63;   // wave h handles head h

    q_lds[t] = Q[(size_t)n * FDIM + t];
    float xv = x[(size_t)n * FDIM + t];
    if (t < MWORDS) mrow[t] = mask[(size_t)n * MWORDS + t];
    __syncthreads();

    // ---- neighbor compaction (wave 0, deterministic order) ----
    if (t < 64) {
        int total = 0;
        for (int r = 0; r < 2; ++r) {
            int w = r * 64 + t;
            uint32_t bits = mrow[w];
            int c = __popc(bits);
            int scan = c;
            #pragma unroll
            for (int off = 1; off < 64; off <<= 1) {
                int u = __shfl_up(scan, off);
                if (t >= off) scan += u;
            }
            int base = total + scan - c;
            while (bits) {
                int b = __ffs(bits) - 1;
                list[base++] = (unsigned short)(w * 32 + b);
                bits &= bits - 1;
            }
            total += __shfl(scan, 63);
        }
        if (t == 0) cnt_s = total;
    }
    __syncthreads();
    int cnt = cnt_s;   // >= 1 (self-loop)

    const float4* qh = (const float4*)(q_lds + h * HD);

    // ---- pass 1: scores + online softmax stats ----
    float mi = -INFINITY, li = 0.f;
    for (int i = lane; i < cnt; i += 64) {
        int m = list[i];
        const float4* kp = (const float4*)(K + (size_t)m * FDIM + h * HD);
        float s = 0.f;
        #pragma unroll
        for (int j = 0; j < HD / 4; ++j) {
            float4 a = qh[j], b = kp[j];
            s += a.x * b.x + a.y * b.y + a.z * b.z + a.w * b.w;
        }
        s *= 0.125f;
        if (i < SCAP) sv[h][i] = s;
        float nm = fmaxf(mi, s);
        li = li * __expf(mi - nm) + __expf(s - nm);
        mi = nm;
    }
    #pragma unroll
    for (int off = 32; off; off >>= 1) {
        float mo = __shfl_xor(mi, off);
        float lo = __shfl_xor(li, off);
        float nm = fmaxf(mi, mo);
        float ea = (nm == -INFINITY) ? 0.f : __expf(mi - nm);
        float eb = (nm == -INFINITY) ? 0.f : __expf(mo - nm);
        li = li * ea + lo * eb;
        mi = nm;
    }
    float M = mi;
    float Linv = 1.f / li;
    if (lane == 0) {
        stats[((size_t)h * NNODES + n) * 2 + 0] = M;
        stats[((size_t)h * NNODES + n) * 2 + 1] = Linv;
    }

    // ---- convert cached scores to probabilities (same wave: no barrier) ----
    int cm = min(cnt, SCAP);
    for (int i = lane; i < cm; i += 64)
        sv[h][i] = __expf(sv[h][i] - M) * Linv;

    // ---- PV: lane = output dim; 4 independent accumulators ----
    const float* vb = V + (size_t)h * HD + lane;
    float o0 = 0.f, o1 = 0.f, o2 = 0.f, o3 = 0.f;
    int j = 0;
    for (; j + 3 < cm; j += 4) {
        int m0 = list[j], m1 = list[j + 1], m2 = list[j + 2], m3 = list[j + 3];
        float p0 = sv[h][j], p1 = sv[h][j + 1], p2 = sv[h][j + 2], p3 = sv[h][j + 3];
        o0 = fmaf(p0, vb[(size_t)m0 * FDIM], o0);
        o1 = fmaf(p1, vb[(size_t)m1 * FDIM], o1);
        o2 = fmaf(p2, vb[(size_t)m2 * FDIM], o2);
        o3 = fmaf(p3, vb[(size_t)m3 * FDIM], o3);
    }
    for (; j < cm; ++j)
        o0 = fmaf(sv[h][j], vb[(size_t)list[j] * FDIM], o0);
    for (; j < cnt; ++j) {  // overflow fallback (degree > SCAP): recompute score
        int m = list[j];
        const float4* kp = (const float4*)(K + (size_t)m * FDIM + h * HD);
        float s = 0.f;
        #pragma unroll
        for (int jj = 0; jj < HD / 4; ++jj) {
            float4 a = qh[jj], b = kp[jj];
            s += a.x * b.x + a.y * b.y + a.z * b.z + a.w * b.w;
        }
        o0 = fmaf(__expf(s * 0.125f - M) * Linv, vb[(size_t)m * FDIM], o0);
    }
    float o = (o0 + o1) + (o2 + o3);

    // ---- residual + LayerNorm (wave shuffle reduce, 1 barrier) ----
    float y = o + xv;
    float s1 = y, s2 = y * y;
    #pragma unroll
    for (int off = 32; off; off >>= 1) {
        s1 += __shfl_xor(s1, off);
        s2 += __shfl_xor(s2, off);
    }
    if (lane == 0) { red0[h] = s1; red1[h] = s2; }
    __syncthreads();
    float ts1 = (red0[0] + red0[1]) + (red0[2] + red0[3]);
    float ts2 = (red1[0] + red1[1]) + (red1[2] + red1[3]);
    float mu = ts1 * (1.f / 256.f);
    float var = ts2 * (1.f / 256.f) - mu * mu;
    out[(size_t)n * FDIM + t] = (y - mu) * rsqrtf(var + 1e-5f) * ln_g[t] + ln_b[t];
}

// ---------------- scatter nonzeros for rows [rowLo,rowHi) + optional fill ----------------
__global__ __launch_bounds__(256) void k_scatter_fill(
    const int* __restrict__ ei, int E, int nsb,
    const float* __restrict__ qkv, const float* __restrict__ stats,
    float* __restrict__ attn, int rowLo, int rowHi,
    unsigned long long fillBeg, unsigned long long fillEnd)
{
    int t = threadIdx.x;
    if (blockIdx.x >= nsb) {                 // filler blocks
        fill_zero((f4*)attn, (size_t)fillBeg, (size_t)fillEnd, blockIdx.x - nsb, t);
        return;
    }
    int idx = blockIdx.x * 256 + t;
    if (idx >= E * NH) return;
    int e = idx >> 2;
    int h = idx & 3;          // 4 consecutive threads share one edge -> coalesced row reads
    int r = ei[e];
    int c = ei[E + e];
    int row = h * NNODES + r;
    if (row < rowLo || row >= rowHi) return;

    const float* Q = qkv;
    const float* K = qkv + (size_t)NNODES * FDIM;
    const float4* qp = (const float4*)(Q + (size_t)r * FDIM + h * HD);
    const float4* kp = (const float4*)(K + (size_t)c * FDIM + h * HD);
    float s = 0.f;
    #pragma unroll
    for (int j = 0; j < HD / 4; ++j) {
        float4 a = qp[j], b = kp[j];
        s += a.x * b.x + a.y * b.y + a.z * b.z + a.w * b.w;
    }
    float M = stats[(size_t)row * 2 + 0];
    float Linv = stats[(size_t)row * 2 + 1];
    // duplicates in the edge list write the same value -> benign race
    attn[(size_t)row * NNODES + c] = __expf(s * 0.125f - M) * Linv;
}

extern "C" void kernel_launch(void* const* d_in, const int* in_sizes, int n_in,
                              void* d_out, int out_size, void* d_ws, size_t ws_size,
                              hipStream_t stream)
{
    const float* x    = (const float*)d_in[0];
    const int*   ei   = (const int*)d_in[1];
    const float* Wq   = (const float*)d_in[2];
    const float* bq   = (const float*)d_in[3];
    const float* Wk   = (const float*)d_in[4];
    const float* bk   = (const float*)d_in[5];
    const float* Wv   = (const float*)d_in[6];
    const float* bv   = (const float*)d_in[7];
    const float* ln_g = (const float*)d_in[8];
    const float* ln_b = (const float*)d_in[9];
    float* out = (float*)d_out;
    float* attn = out + (size_t)NNODES * FDIM;

    int E = in_sizes[1] / 2;

    // ws layout (floats): Wt[3*256*256] | QKV[3*4096*256] | mask[4096*128 u32] | stats[4*4096*2]
    float* Wt  = (float*)d_ws;
    float* qkv = Wt + 3 * FDIM * FDIM;
    uint32_t* mask = (uint32_t*)(qkv + 3 * (size_t)NNODES * FDIM);
    float* stats = (float*)(mask + (size_t)NNODES * MWORDS);

    hipMemsetAsync(mask, 0, (size_t)NNODES * MWORDS * sizeof(uint32_t), stream);

    dim3 tb(32, 8);
    k_transpose_w<<<dim3(8, 8, 3), tb, 0, stream>>>(Wq, Wk, Wv, Wt);
    k_mask_build<<<(E + 255) / 256, 256, 0, stream>>>(ei, E, mask);

    // D3: qkv (768 blocks) + fill rows [0, R0)
    k_qkv_fill<<<3 * (NNODES / TN) + NFB, 256, 0, stream>>>(x, Wt, bq, bk, bv, qkv, attn);

    // D4: attn stats/out (4096 blocks) + fill rows [R0, R1)
    k_attn_fill<<<NNODES + NFB, 256, 0, stream>>>(qkv, mask, x, ln_g, ln_b, out, stats, attn);

    // D5: scatter rows [0, R1) + fill rows [R1, 16384)
    int nsb = (E * NH + 255) / 256;
    k_scatter_fill<<<nsb + NFB, 256, 0, stream>>>(
        ei, E, nsb, qkv, stats, attn, 0, R1,
        (unsigned long long)R1 * ROW4, (unsigned long long)TOTROWS * ROW4);

    // D6: scatter tail rows [R1, 16384), no fill
    k_scatter_fill<<<nsb, 256, 0, stream>>>(
        ei, E, nsb, qkv, stats, attn, R1, TOTROWS, 0ull, 0ull);
}

// Round 5
// 206.919 us; speedup vs baseline: 1.7967x; 1.0242x over previous
//
#include <hip/hip_runtime.h>
#include <stdint.h>

#define NNODES 4096
#define FDIM 256
#define NH 4
#define HD 64
#define MWORDS 128   // 4096/32 mask words per row
#define SCAP 512     // score cache per head (fallback recompute beyond)
#define TOTROWS (NH * NNODES)          // 16384 attn rows (16 KB each)
#define ROW4 (NNODES / 4)              // 1024 float4 per row
#define R0 6144                        // fill split (rows): D3 fills [0,R0), D4 fills [R0,end)
#define FB3 24576                      // (R0*ROW4)/256       filler blocks in D3
#define FB4 40960                      // ((TOTROWS-R0)*ROW4)/256 filler blocks in D4

typedef float f4 __attribute__((ext_vector_type(4)));

// one 16B store per thread (rocclr fillBufferAligned shape)
__device__ __forceinline__ void fill_one(f4* __restrict__ attn4, size_t beg, size_t end,
                                         int fid, int t)
{
    f4 z = {0.f, 0.f, 0.f, 0.f};
    size_t i = beg + (size_t)fid * 256 + t;
    if (i < end) attn4[i] = z;
}

// ---------------- W transpose (3x 256x256) ----------------
__global__ __launch_bounds__(256) void k_transpose_w(
    const float* __restrict__ Wq, const float* __restrict__ Wk,
    const float* __restrict__ Wv, float* __restrict__ Wt)
{
    __shared__ float tile[32][33];
    int mat = blockIdx.z;
    const float* W = mat == 0 ? Wq : (mat == 1 ? Wk : Wv);
    float* dst = Wt + (size_t)mat * FDIM * FDIM;
    int r0 = blockIdx.y * 32, c0 = blockIdx.x * 32;
    int tx = threadIdx.x, ty = threadIdx.y;  // block (32,8)
    for (int i = ty; i < 32; i += 8)
        tile[i][tx] = W[(size_t)(r0 + i) * FDIM + c0 + tx];
    __syncthreads();
    for (int i = ty; i < 32; i += 8)
        dst[(size_t)(c0 + i) * FDIM + r0 + tx] = tile[tx][i];
}

// ---------------- adjacency bitmask ----------------
__global__ void k_mask_build(const int* __restrict__ ei, int E, uint32_t* __restrict__ mask)
{
    int e = blockIdx.x * 256 + threadIdx.x;
    if (e >= E) return;
    int r = ei[e];
    int c = ei[E + e];
    atomicOr(&mask[(size_t)r * MWORDS + (c >> 5)], 1u << (c & 31));
}

// ---------------- QKV projection + fill rows [0, R0) ----------------
#define TN 16
__global__ __launch_bounds__(256) void k_qkv_fill(
    const float* __restrict__ x, const float* __restrict__ Wt,
    const float* __restrict__ bq, const float* __restrict__ bk, const float* __restrict__ bv,
    float* __restrict__ qkv, float* __restrict__ attn)
{
    int t = threadIdx.x;
    if (blockIdx.x >= 3 * (NNODES / TN)) {   // filler blocks: one f4 store each
        fill_one((f4*)attn, 0, (size_t)R0 * ROW4, blockIdx.x - 3 * (NNODES / TN), t);
        return;
    }
    int mat = blockIdx.x >> 8;               // NNODES/TN == 256 blocks per matrix
    int n0 = (blockIdx.x & 255) * TN;
    const float* W = Wt + (size_t)mat * FDIM * FDIM;   // [k][t]
    const float* bias = mat == 0 ? bq : (mat == 1 ? bk : bv);
    float* dst = qkv + (size_t)mat * NNODES * FDIM;
    __shared__ float xl[TN][FDIM + 4];
    for (int f = t; f < TN * (FDIM / 4); f += 256) {
        int n = f >> 6, c4 = f & 63;
        float4 v = ((const float4*)(x + (size_t)(n0 + n) * FDIM))[c4];
        *(float4*)&xl[n][c4 * 4] = v;
    }
    __syncthreads();
    float acc[TN];
    #pragma unroll
    for (int n = 0; n < TN; ++n) acc[n] = 0.f;
    for (int k4 = 0; k4 < FDIM / 4; ++k4) {
        float w0 = W[(size_t)(k4 * 4 + 0) * FDIM + t];
        float w1 = W[(size_t)(k4 * 4 + 1) * FDIM + t];
        float w2 = W[(size_t)(k4 * 4 + 2) * FDIM + t];
        float w3 = W[(size_t)(k4 * 4 + 3) * FDIM + t];
        #pragma unroll
        for (int n = 0; n < TN; ++n) {
            float4 xv = *(const float4*)&xl[n][k4 * 4];
            acc[n] = fmaf(w0, xv.x, acc[n]);
            acc[n] = fmaf(w1, xv.y, acc[n]);
            acc[n] = fmaf(w2, xv.z, acc[n]);
            acc[n] = fmaf(w3, xv.w, acc[n]);
        }
    }
    float bb = bias[t];
    #pragma unroll
    for (int n = 0; n < TN; ++n)
        dst[(size_t)(n0 + n) * FDIM + t] = acc[n] + bb;
}

// ---------------- sparse attention + residual + LN, + fill rows [R0, end) ----------------
__global__ __launch_bounds__(256) void k_attn_fill(
    const float* __restrict__ qkv, const uint32_t* __restrict__ mask,
    const float* __restrict__ x, const float* __restrict__ ln_g, const float* __restrict__ ln_b,
    float* __restrict__ out, float* __restrict__ stats, float* __restrict__ attn)
{
    int t = threadIdx.x;
    if (blockIdx.x >= NNODES) {              // filler blocks: one f4 store each
        fill_one((f4*)attn, (size_t)R0 * ROW4, (size_t)TOTROWS * ROW4, blockIdx.x - NNODES, t);
        return;
    }

    const float* Q = qkv;
    const float* K = qkv + (size_t)NNODES * FDIM;
    const float* V = qkv + 2 * (size_t)NNODES * FDIM;

    __shared__ float q_lds[FDIM];
    __shared__ uint32_t mrow[MWORDS];
    __shared__ unsigned short list[NNODES];
    __shared__ float sv[NH][SCAP];
    __shared__ float red0[NH], red1[NH];
    __shared__ int cnt_s;

    int n = blockIdx.x;
    int h = t >> 6, lane = t & 63;   // wave h handles head h

    q_lds[t] = Q[(size_t)n * FDIM + t];
    float xv = x[(size_t)n * FDIM + t];
    if (t < MWORDS) mrow[t] = mask[(size_t)n * MWORDS + t];
    __syncthreads();

    // ---- neighbor compaction (wave 0, deterministic order) ----
    if (t < 64) {
        int total = 0;
        for (int r = 0; r < 2; ++r) {
            int w = r * 64 + t;
            uint32_t bits = mrow[w];
            int c = __popc(bits);
            int scan = c;
            #pragma unroll
            for (int off = 1; off < 64; off <<= 1) {
                int u = __shfl_up(scan, off);
                if (t >= off) scan += u;
            }
            int base = total + scan - c;
            while (bits) {
                int b = __ffs(bits) - 1;
                list[base++] = (unsigned short)(w * 32 + b);
                bits &= bits - 1;
            }
            total += __shfl(scan, 63);
        }
        if (t == 0) cnt_s = total;
    }
    __syncthreads();
    int cnt = cnt_s;   // >= 1 (self-loop)

    const float4* qh = (const float4*)(q_lds + h * HD);

    // ---- pass 1: scores + online softmax stats ----
    float mi = -INFINITY, li = 0.f;
    for (int i = lane; i < cnt; i += 64) {
        int m = list[i];
        const float4* kp = (const float4*)(K + (size_t)m * FDIM + h * HD);
        float s = 0.f;
        #pragma unroll
        for (int j = 0; j < HD / 4; ++j) {
            float4 a = qh[j], b = kp[j];
            s += a.x * b.x + a.y * b.y + a.z * b.z + a.w * b.w;
        }
        s *= 0.125f;
        if (i < SCAP) sv[h][i] = s;
        float nm = fmaxf(mi, s);
        li = li * __expf(mi - nm) + __expf(s - nm);
        mi = nm;
    }
    #pragma unroll
    for (int off = 32; off; off >>= 1) {
        float mo = __shfl_xor(mi, off);
        float lo = __shfl_xor(li, off);
        float nm = fmaxf(mi, mo);
        float ea = (nm == -INFINITY) ? 0.f : __expf(mi - nm);
        float eb = (nm == -INFINITY) ? 0.f : __expf(mo - nm);
        li = li * ea + lo * eb;
        mi = nm;
    }
    float M = mi;
    float Linv = 1.f / li;
    if (lane == 0) {
        stats[((size_t)h * NNODES + n) * 2 + 0] = M;
        stats[((size_t)h * NNODES + n) * 2 + 1] = Linv;
    }

    // ---- convert cached scores to probabilities (same wave: no barrier) ----
    int cm = min(cnt, SCAP);
    for (int i = lane; i < cm; i += 64)
        sv[h][i] = __expf(sv[h][i] - M) * Linv;

    // ---- PV: lane = output dim; 4 independent accumulators ----
    const float* vb = V + (size_t)h * HD + lane;
    float o0 = 0.f, o1 = 0.f, o2 = 0.f, o3 = 0.f;
    int j = 0;
    for (; j + 3 < cm; j += 4) {
        int m0 = list[j], m1 = list[j + 1], m2 = list[j + 2], m3 = list[j + 3];
        float p0 = sv[h][j], p1 = sv[h][j + 1], p2 = sv[h][j + 2], p3 = sv[h][j + 3];
        o0 = fmaf(p0, vb[(size_t)m0 * FDIM], o0);
        o1 = fmaf(p1, vb[(size_t)m1 * FDIM], o1);
        o2 = fmaf(p2, vb[(size_t)m2 * FDIM], o2);
        o3 = fmaf(p3, vb[(size_t)m3 * FDIM], o3);
    }
    for (; j < cm; ++j)
        o0 = fmaf(sv[h][j], vb[(size_t)list[j] * FDIM], o0);
    for (; j < cnt; ++j) {  // overflow fallback (degree > SCAP): recompute score
        int m = list[j];
        const float4* kp = (const float4*)(K + (size_t)m * FDIM + h * HD);
        float s = 0.f;
        #pragma unroll
        for (int jj = 0; jj < HD / 4; ++jj) {
            float4 a = qh[jj], b = kp[jj];
            s += a.x * b.x + a.y * b.y + a.z * b.z + a.w * b.w;
        }
        o0 = fmaf(__expf(s * 0.125f - M) * Linv, vb[(size_t)m * FDIM], o0);
    }
    float o = (o0 + o1) + (o2 + o3);

    // ---- residual + LayerNorm (wave shuffle reduce, 1 barrier) ----
    float y = o + xv;
    float s1 = y, s2 = y * y;
    #pragma unroll
    for (int off = 32; off; off >>= 1) {
        s1 += __shfl_xor(s1, off);
        s2 += __shfl_xor(s2, off);
    }
    if (lane == 0) { red0[h] = s1; red1[h] = s2; }
    __syncthreads();
    float ts1 = (red0[0] + red0[1]) + (red0[2] + red0[3]);
    float ts2 = (red1[0] + red1[1]) + (red1[2] + red1[3]);
    float mu = ts1 * (1.f / 256.f);
    float var = ts2 * (1.f / 256.f) - mu * mu;
    out[(size_t)n * FDIM + t] = (y - mu) * rsqrtf(var + 1e-5f) * ln_g[t] + ln_b[t];
}

// ---------------- scatter nonzeros (all rows; runs after fill completes) ----------------
__global__ __launch_bounds__(256) void k_scatter(
    const int* __restrict__ ei, int E,
    const float* __restrict__ qkv, const float* __restrict__ stats,
    float* __restrict__ attn)
{
    int idx = blockIdx.x * 256 + threadIdx.x;
    if (idx >= E * NH) return;
    int e = idx >> 2;
    int h = idx & 3;          // 4 consecutive threads share one edge -> coalesced row reads
    int r = ei[e];
    int c = ei[E + e];

    const float* Q = qkv;
    const float* K = qkv + (size_t)NNODES * FDIM;
    const float4* qp = (const float4*)(Q + (size_t)r * FDIM + h * HD);
    const float4* kp = (const float4*)(K + (size_t)c * FDIM + h * HD);
    float s = 0.f;
    #pragma unroll
    for (int j = 0; j < HD / 4; ++j) {
        float4 a = qp[j], b = kp[j];
        s += a.x * b.x + a.y * b.y + a.z * b.z + a.w * b.w;
    }
    size_t row = (size_t)h * NNODES + r;
    float M = stats[row * 2 + 0];
    float Linv = stats[row * 2 + 1];
    // duplicates in the edge list write the same value -> benign race
    attn[row * NNODES + c] = __expf(s * 0.125f - M) * Linv;
}

extern "C" void kernel_launch(void* const* d_in, const int* in_sizes, int n_in,
                              void* d_out, int out_size, void* d_ws, size_t ws_size,
                              hipStream_t stream)
{
    const float* x    = (const float*)d_in[0];
    const int*   ei   = (const int*)d_in[1];
    const float* Wq   = (const float*)d_in[2];
    const float* bq   = (const float*)d_in[3];
    const float* Wk   = (const float*)d_in[4];
    const float* bk   = (const float*)d_in[5];
    const float* Wv   = (const float*)d_in[6];
    const float* bv   = (const float*)d_in[7];
    const float* ln_g = (const float*)d_in[8];
    const float* ln_b = (const float*)d_in[9];
    float* out = (float*)d_out;
    float* attn = out + (size_t)NNODES * FDIM;

    int E = in_sizes[1] / 2;

    // ws layout (floats): Wt[3*256*256] | QKV[3*4096*256] | mask[4096*128 u32] | stats[4*4096*2]
    float* Wt  = (float*)d_ws;
    float* qkv = Wt + 3 * FDIM * FDIM;
    uint32_t* mask = (uint32_t*)(qkv + 3 * (size_t)NNODES * FDIM);
    float* stats = (float*)(mask + (size_t)NNODES * MWORDS);

    hipMemsetAsync(mask, 0, (size_t)NNODES * MWORDS * sizeof(uint32_t), stream);

    dim3 tb(32, 8);
    k_transpose_w<<<dim3(8, 8, 3), tb, 0, stream>>>(Wq, Wk, Wv, Wt);
    k_mask_build<<<(E + 255) / 256, 256, 0, stream>>>(ei, E, mask);

    // D3: qkv (768 blocks) + one-store-per-thread fill of rows [0, R0)
    k_qkv_fill<<<3 * (NNODES / TN) + FB3, 256, 0, stream>>>(x, Wt, bq, bk, bv, qkv, attn);

    // D4: attn stats/out (4096 blocks) + fill of rows [R0, 16384)
    k_attn_fill<<<NNODES + FB4, 256, 0, stream>>>(qkv, mask, x, ln_g, ln_b, out, stats, attn);

    // D5: scatter all nonzeros (fill already complete)
    k_scatter<<<(E * NH + 255) / 256, 256, 0, stream>>>(ei, E, qkv, stats, attn);
}